// Round 5
// baseline (392.954 us; speedup 1.0000x reference)
//
#include <hip/hip_runtime.h>

#define BATCH  16
#define CCH    128
#define TDIM   16384
#define MROWS  256                   // 2C
#define NCHUNK 16
#define KC     1024                  // k per chunk
#define BKS    128                   // k per step
#define NSTEP  8                     // KC / BKS
#define STEPB  65536u                // bytes per step image: 256 rows * 128 bf16 * 2B
#define REGSH  262144u               // shorts per (b,chunk) region = NSTEP * 32768
#define LDSBYTES (2u * STEPB)        // 128 KiB double buffer
#define GRAM   (MROWS * MROWS)       // 65536

typedef __attribute__((ext_vector_type(8))) short bf16x8;
typedef __attribute__((ext_vector_type(4))) float f32x4;
typedef __attribute__((ext_vector_type(8))) unsigned short u16x8;
typedef const __attribute__((address_space(1))) unsigned int* gptr_t;
typedef __attribute__((address_space(3))) unsigned int* lptr_t;

__device__ __forceinline__ unsigned short f2bf(float x) {
  // RTNE fp32 -> bf16 (inputs are finite normals; no NaN path needed)
  unsigned int u = __float_as_uint(x);
  u += 0x7fffu + ((u >> 16) & 1u);
  return (unsigned short)(u >> 16);
}

// ---------------------------------------------------------------------------
// Pass 1: pack fp32 inputs into bf16 "LDS images".
// Packed layout: region(b,c) [512 KB] = [step s][row R][chunk'][8 bf16] where
// chunk' = ((klocal>>3) ^ (R&7))  (XOR swizzle baked into the layout so the
// gram kernel can DMA it linearly and read conflict-free: rule #21 / m173).
// Reads: fully contiguous per row (8 KB per block-iteration). Writes: 256 B
// granules at 64 KB stride (posted; pain goes on the write side).
// ---------------------------------------------------------------------------
__global__ __launch_bounds__(256) void pack_kernel(
    const float* __restrict__ fs, const float* __restrict__ ft,
    unsigned short* __restrict__ pk)
{
  const int id  = blockIdx.x;          // 0..4095
  const int tau = id >> 11;            // 0: fs, 1: ft
  const int b   = (id >> 7) & 15;
  const int row = id & 127;
  const int R   = tau * CCH + row;     // packed row index 0..255
  const int r7  = R & 7;
  const float* src = (tau ? ft : fs) + (size_t)(b * CCH + row) * TDIM;
  unsigned short* dstb = pk + (size_t)b * NCHUNK * REGSH + (size_t)R * 128;

  #pragma unroll 1
  for (int it = 0; it < 8; ++it) {
    const int k = it * 2048 + threadIdx.x * 8;
    f32x4 lo = *(const f32x4*)(src + k);
    f32x4 hi = *(const f32x4*)(src + k + 4);
    u16x8 p;
    p[0] = f2bf(lo.x); p[1] = f2bf(lo.y); p[2] = f2bf(lo.z); p[3] = f2bf(lo.w);
    p[4] = f2bf(hi.x); p[5] = f2bf(hi.y); p[6] = f2bf(hi.z); p[7] = f2bf(hi.w);
    const int c  = k >> 10;            // chunk
    const int s  = (k >> 7) & 7;       // step within chunk
    const int cl = (k >> 3) & 15;      // logical 8-elem chunk within step-row
    unsigned short* dst = dstb + (size_t)c * REGSH + (unsigned)s * 32768u
                        + (unsigned)((cl ^ r7) << 3);
    *(u16x8*)dst = p;
  }
}

// One k-sub-block (32 k) of MFMA from the (swizzled) bf16 step image.
__device__ __forceinline__ void compute_kk(
    const unsigned short* bp, f32x4 (&acc)[4][8], int kk,
    int wr, int wc, int llo, int lhi)
{
  bf16x8 af[4], bfr[8];
  #pragma unroll
  for (int i = 0; i < 4; ++i) {
    const int R = wr * 64 + i * 16 + llo;
    af[i] = *(const bf16x8*)(bp + R * 128 + (((kk * 4 + lhi) ^ (R & 7)) << 3));
  }
  #pragma unroll
  for (int j = 0; j < 8; ++j) {
    const int R = wc * 128 + j * 16 + llo;
    bfr[j] = *(const bf16x8*)(bp + R * 128 + (((kk * 4 + lhi) ^ (R & 7)) << 3));
  }
  #pragma unroll
  for (int i = 0; i < 4; ++i)
    #pragma unroll
    for (int j = 0; j < 8; ++j)
      acc[i][j] = __builtin_amdgcn_mfma_f32_16x16x32_bf16(af[i], bfr[j], acc[i][j], 0, 0, 0);
}

// ---------------------------------------------------------------------------
// Pass 2: gram. Each block reads its private 512 KB packed region LINEARLY
// via global_load_lds (16 B), 2-deep LDS pipeline, counted vmcnt.
// Epilogue: atomicAdd into the 4 MB accumulated gram (kills the partial
// write + strided gather tail).
// ---------------------------------------------------------------------------
__global__ __launch_bounds__(512, 2) void gram_kernel(
    const unsigned short* __restrict__ pk, float* __restrict__ gram)
{
  extern __shared__ __attribute__((aligned(16))) char smraw[];

  const int tid  = threadIdx.x;
  const int bidx = blockIdx.x;         // b*16 + chunk
  const int b    = bidx >> 4;
  const char* reg = (const char*)(pk + (size_t)bidx * REGSH);

  const int lane = tid & 63;
  const int w    = tid >> 6;           // wave 0..7
  const int wr   = w & 3;              // rows [wr*64, wr*64+64)
  const int wc   = w >> 2;             // cols [wc*128, wc*128+128)
  const int lhi  = lane >> 4;          // 0..3
  const int llo  = lane & 15;

  f32x4 acc[4][8];
  #pragma unroll
  for (int i = 0; i < 4; ++i)
    #pragma unroll
    for (int j = 0; j < 8; ++j)
      acc[i][j] = (f32x4){0.f, 0.f, 0.f, 0.f};

  // issue stage s: 64 KB linear copy, 8 x 16 B per thread
  #define ISSUE_STAGE(s)                                                     \
    {                                                                        \
      const char* g = reg + (size_t)(s) * STEPB;                             \
      char* l = smraw + (unsigned)((s) & 1) * STEPB;                         \
      _Pragma("unroll")                                                      \
      for (int q = 0; q < 8; ++q)                                            \
        __builtin_amdgcn_global_load_lds(                                    \
            (gptr_t)(g + q * 8192 + tid * 16),                               \
            (lptr_t)(l + q * 8192 + tid * 16), 16, 0, 0);                    \
    }

  ISSUE_STAGE(0);
  ISSUE_STAGE(1);

  #pragma unroll 1
  for (int s = 0; s < NSTEP; ++s) {
    // stage s landed when <= 8 loads (stage s+1) remain outstanding
    if (s < NSTEP - 1) asm volatile("s_waitcnt vmcnt(8)" ::: "memory");
    else               asm volatile("s_waitcnt vmcnt(0)" ::: "memory");
    __builtin_amdgcn_s_barrier();          // all waves' DMA for stage s done
    asm volatile("" ::: "memory");

    const unsigned short* bp = (const unsigned short*)(smraw + (unsigned)(s & 1) * STEPB);
    compute_kk(bp, acc, 0, wr, wc, llo, lhi);
    compute_kk(bp, acc, 1, wr, wc, llo, lhi);
    compute_kk(bp, acc, 2, wr, wc, llo, lhi);
    compute_kk(bp, acc, 3, wr, wc, llo, lhi);

    asm volatile("s_waitcnt lgkmcnt(0)" ::: "memory");  // my LDS reads done
    __builtin_amdgcn_s_barrier();          // safe to overwrite buffer (s&1)
    asm volatile("" ::: "memory");

    if (s + 2 < NSTEP) ISSUE_STAGE(s + 2);
  }
  #undef ISSUE_STAGE

  // epilogue: accumulate into gram[b] (4 MB total across batches)
  // C/D layout (m89/m91 verified): col = lane&15, row = (lane>>4)*4 + reg
  float* out = gram + (size_t)b * GRAM;
  #pragma unroll
  for (int i = 0; i < 4; ++i) {
    int row0 = wr * 64 + i * 16 + lhi * 4;
    #pragma unroll
    for (int j = 0; j < 8; ++j) {
      int col = wc * 128 + j * 16 + llo;
      #pragma unroll
      for (int r = 0; r < 4; ++r)
        atomicAdd(&out[(size_t)(row0 + r) * MROWS + col], acc[i][j][r]);
    }
  }
}

// Inverse norms from the accumulated gram diagonal.
__global__ __launch_bounds__(256) void norms_kernel(
    const float* __restrict__ gram, float* __restrict__ norms)
{
  int b = blockIdx.x;
  int d = threadIdx.x;  // 0..255
  float g = gram[(size_t)b * GRAM + (size_t)d * (MROWS + 1)];
  float n = sqrtf(fmaxf(g, 0.f));
  n = fmaxf(n, 1e-12f);   // F.normalize eps
  norms[b * MROWS + d] = 1.0f / n;
}

// grid = BATCH*64; each block handles 1024 contiguous gram elements.
__global__ __launch_bounds__(256) void loss_kernel(
    const float* __restrict__ gram, const float* __restrict__ norms,
    float* __restrict__ out)
{
  int b     = blockIdx.x >> 6;
  int strip = blockIdx.x & 63;
  int e0    = strip * 1024 + threadIdx.x * 4;
  const float* nb = norms + b * MROWS;

  f32x4 g = *(const f32x4*)(gram + (size_t)b * GRAM + e0);

  int i  = e0 >> 8;
  int j0 = e0 & 255;
  float ri = nb[i];
  float accl = 0.f;
  #pragma unroll
  for (int q = 0; q < 4; ++q) {
    int j = j0 + q;
    float gh = g[q] * ri * nb[j];
    // w_i*w_j: +1 within ss / tt blocks, -1 in st / ts blocks
    float sgn = ((i < CCH) == (j < CCH)) ? 1.f : -1.f;
    accl += sgn * gh * gh;
  }
  // block reduction
  #pragma unroll
  for (int off = 32; off > 0; off >>= 1)
    accl += __shfl_down(accl, off, 64);
  __shared__ float red[4];
  if ((threadIdx.x & 63) == 0) red[threadIdx.x >> 6] = accl;
  __syncthreads();
  if (threadIdx.x == 0) {
    float t = red[0] + red[1] + red[2] + red[3];
    atomicAdd(out, t * (1.0f / (float)(BATCH * CCH * CCH)));
  }
}

extern "C" void kernel_launch(void* const* d_in, const int* in_sizes, int n_in,
                              void* d_out, int out_size, void* d_ws, size_t ws_size,
                              hipStream_t stream) {
  const float* fs = (const float*)d_in[0];
  const float* ft = (const float*)d_in[1];
  float* out = (float*)d_out;
  float* wsf = (float*)d_ws;

  float* norms = wsf;                                   // 4096 floats (16 KB)
  float* gram  = wsf + 4096;                            // 16 * 65536 floats (4 MB)
  unsigned short* pk = (unsigned short*)(gram + (size_t)BATCH * GRAM);  // 128 MB

  static int lds_raised = 0;
  if (!lds_raised) {
    (void)hipFuncSetAttribute(reinterpret_cast<const void*>(gram_kernel),
                              hipFuncAttributeMaxDynamicSharedMemorySize, LDSBYTES);
    lds_raised = 1;
  }

  (void)hipMemsetAsync(d_out, 0, sizeof(float), stream);
  (void)hipMemsetAsync(gram, 0, (size_t)BATCH * GRAM * sizeof(float), stream);

  pack_kernel<<<dim3(2 * BATCH * CCH), dim3(256), 0, stream>>>(fs, ft, pk);
  gram_kernel<<<dim3(BATCH * NCHUNK), dim3(512), LDSBYTES, stream>>>(pk, gram);
  norms_kernel<<<dim3(BATCH), dim3(256), 0, stream>>>(gram, norms);
  loss_kernel<<<dim3(BATCH * 64), dim3(256), 0, stream>>>(gram, norms, out);
}